// Round 3
// baseline (206.567 us; speedup 1.0000x reference)
//
#include <hip/hip_runtime.h>
#include <math.h>

// Problem constants
#define BS    2048            // batch
#define NROW  4096            // B*V = N
#define EDIM  256
#define INVT  (1.0f/0.07f)
#define NBLK  (64*16)         // main grid blocks

typedef float  float4v __attribute__((ext_vector_type(4)));
typedef short  short8v __attribute__((ext_vector_type(8)));

static __device__ __forceinline__ unsigned short f2bf(float x) {
    // round-to-nearest-even f32 -> bf16 (inputs are finite)
    unsigned u = __builtin_bit_cast(unsigned, x);
    u += 0x7fffu + ((u >> 16) & 1u);
    return (unsigned short)(u >> 16);
}

// ---------------- prep kernel: normalize + label bits + zero accumulators ----
// blocks 0..4095: row normalize (wave w = head w); blocks 4096..4103: labels + zeroing
__global__ void prep_kernel(const float* __restrict__ feat, const float* __restrict__ labels,
                            unsigned short* __restrict__ fnb, unsigned* __restrict__ bits,
                            float* __restrict__ zacc) {
    const int b = blockIdx.x, t = threadIdx.x;
    if (b < NROW) {
        int bb = b & (BS - 1);
        int v = b >> 11;
        float x = feat[(size_t)bb * (2 * EDIM) + (size_t)v * EDIM + t];
        float ss = x * x;
#pragma unroll
        for (int off = 32; off > 0; off >>= 1)
            ss += __shfl_xor(ss, off, 64);
        float nrm = fmaxf(sqrtf(ss), 1e-12f);
        fnb[(size_t)b * EDIM + t] = f2bf(x / nrm);
    } else {
        int g = (b - NROW) * 256 + t;   // 0..2047
        unsigned bb = 0;
#pragma unroll
        for (int d = 0; d < 10; ++d)
            bb |= (labels[g * 10 + d] != 0.0f ? 1u : 0u) << d;
        bits[g] = bb;
        // zero S (N*4), Num (N), Cnt (N*4), red[2], done[1] = N*9+3 words
        for (int k = g; k < NROW * 9 + 3; k += 2048) zacc[k] = 0.0f;
    }
}

// ---------------- main kernel: barrier-free, LDS-free, reg-direct B ----------
// grid (64, 16), block 256 = 4 waves, all waves independent.
// Wave w: i-rows [bx*64 + w*16, +16) x j in [by*256, +256) as 16 steps of 16 j.
// B-fragment layout for mfma_16x16x32_bf16 == A-fragment layout == a row-major
// row of fnb (lane -> n = lane&15, k = quad*8 + e per 32-wide kk chunk), so B
// loads straight from global (fnb is 2MB, L2-resident) into regs -- no LDS,
// no __syncthreads, no swizzle, no bank conflicts in the hot loop.
// Round-1/2 post-mortem: staged+barriered subtile pipeline was 2.2x SLOWER
// than serial (125 vs 57 us) -- barrier vmcnt(0) drains + LDS round-trip at
// ~1.7 waves/SIMD was the stall class. This removes the class entirely.
// Named bfA/bfB double buffer (static indexing, rule #20): 8 loads always in
// flight across ~120 epilogue instrs -> compiler emits counted vmcnt waits.
// C/D layout (m89/m91): col = lane&15, row = (lane>>4)*4 + reg.
__global__ __launch_bounds__(256, 3) void main_kernel(
    const unsigned short* __restrict__ fnb, const unsigned* __restrict__ bits,
    float* __restrict__ S, float* __restrict__ Num, float* __restrict__ Cnt,
    unsigned* __restrict__ done, float* __restrict__ out) {

    __shared__ float rwave[8];
    __shared__ unsigned lastFlag;

    const int tid  = threadIdx.x;
    const int lane = tid & 63;
    const int wave = tid >> 6;
    const int quad = lane >> 4;
    const int ml   = lane & 15;
    const int i0   = blockIdx.x * 64 + wave * 16;
    const int jc0  = blockIdx.y * 256;

    // A fragments: af[h][kk], 8 x short8 = 32 VGPRs (rows i0..i0+15)
    short8v af[4][2];
    {
        const unsigned short* ap = fnb + (size_t)(i0 + ml) * EDIM + quad * 8;
#pragma unroll
        for (int h = 0; h < 4; ++h)
#pragma unroll
            for (int kk = 0; kk < 2; ++kk)
                af[h][kk] = *(const short8v*)(ap + h * 64 + kk * 32);
    }

    unsigned ibr[4];
#pragma unroll
    for (int r = 0; r < 4; ++r)
        ibr[r] = bits[(i0 + quad * 4 + r) & (BS - 1)];

    float    Sp[4][4] = {};
    float    np[4] = {};
    unsigned cpk[4] = {};   // per row: 4 x 8-bit argmax-head counts

    struct BF { short8v v[4][2]; };   // one 16-j-row B fragment set (32 VGPR)

    auto LOADB = [&](BF& b, int js) {
        const unsigned short* bp = fnb + (size_t)(jc0 + js * 16 + ml) * EDIM + quad * 8;
#pragma unroll
        for (int h = 0; h < 4; ++h)
#pragma unroll
            for (int kk = 0; kk < 2; ++kk)
                b.v[h][kk] = *(const short8v*)(bp + h * 64 + kk * 32);
    };

    auto STEP = [&](const BF& b, int js) {
        const int j0 = jc0 + js * 16;
        const unsigned jb = bits[(j0 + ml) & (BS - 1)];
        float4v dacc[4];
#pragma unroll
        for (int h = 0; h < 4; ++h) dacc[h] = (float4v){0.f, 0.f, 0.f, 0.f};
#pragma unroll
        for (int h = 0; h < 4; ++h)
#pragma unroll
            for (int kk = 0; kk < 2; ++kk)
                dacc[h] = __builtin_amdgcn_mfma_f32_16x16x32_bf16(af[h][kk], b.v[h][kk], dacc[h], 0, 0, 0);

        const int j = j0 + ml;
#pragma unroll
        for (int r = 0; r < 4; ++r) {
            const int i = i0 + quad * 4 + r;
            const float d0 = dacc[0][r];
            const float d1 = dacc[1][r];
            const float d2 = dacc[2][r];
            const float d3 = dacc[3][r];
            // argmax, first index wins ties
            float bd = d0; int bh = 0;
            if (d1 > bd) { bd = d1; bh = 1; }
            if (d2 > bd) { bd = d2; bh = 2; }
            if (d3 > bd) { bd = d3; bh = 3; }
            const bool off = (i != j);
            const float e0 = __expf(fmaf(d0, INVT, -INVT));
            const float e1 = __expf(fmaf(d1, INVT, -INVT));
            const float e2 = __expf(fmaf(d2, INVT, -INVT));
            const float e3 = __expf(fmaf(d3, INVT, -INVT));
            if (off) {
                Sp[r][0] += e0; Sp[r][1] += e1; Sp[r][2] += e2; Sp[r][3] += e3;
            }
            if (off && (ibr[r] & jb)) {
                np[r] += bd;              // raw dot; * INVT at flush
                cpk[r] += 1u << (bh * 8);
            }
        }
    };

    BF bfA, bfB;
    LOADB(bfA, 0);
    for (int js = 0; js < 16; js += 2) {
        LOADB(bfB, js + 1);
        STEP(bfA, js);
        const int jn = (js + 2 < 16) ? js + 2 : 0;   // last prefetch harmless reload
        LOADB(bfA, jn);
        STEP(bfB, js + 1);
    }

    // reduce the 16 lanes sharing each row, then one global atomic per value
#pragma unroll
    for (int r = 0; r < 4; ++r) {
        const int i = i0 + quad * 4 + r;
        float v[9];
        v[0] = np[r];
#pragma unroll
        for (int h = 0; h < 4; ++h) v[1 + h] = Sp[r][h];
#pragma unroll
        for (int h = 0; h < 4; ++h) v[5 + h] = (float)((cpk[r] >> (8 * h)) & 255u);
#pragma unroll
        for (int k = 0; k < 9; ++k) {
            float x = v[k];
            x += __shfl_xor(x, 1, 64);
            x += __shfl_xor(x, 2, 64);
            x += __shfl_xor(x, 4, 64);
            x += __shfl_xor(x, 8, 64);
            v[k] = x;
        }
        if (ml == 0) {
            atomicAdd(&Num[i], v[0] * INVT);
#pragma unroll
            for (int h = 0; h < 4; ++h) atomicAdd(&S[i * 4 + h], v[1 + h]);
#pragma unroll
            for (int h = 0; h < 4; ++h) atomicAdd(&Cnt[i * 4 + h], v[5 + h]);
        }
    }

    // ---------------- fused final reduction: last finishing block ------------
    __threadfence();          // our atomics visible before done-increment
    __syncthreads();          // all threads' atomics issued+fenced before tid0 signals
    if (tid == 0) lastFlag = (atomicAdd(done, 1u) == NBLK - 1) ? 1u : 0u;
    __syncthreads();
    if (lastFlag) {
        float ls = 0.f, lc = 0.f;
        for (int r2 = tid; r2 < NROW; r2 += 256) {
            // agent-scope atomic loads: bypass non-coherent L1 (values were
            // produced by device-scope atomics from other CUs/XCDs)
            float numr = __hip_atomic_load(&Num[r2], __ATOMIC_RELAXED, __HIP_MEMORY_SCOPE_AGENT);
            float c = 0.f;
#pragma unroll
            for (int h = 0; h < 4; ++h) {
                float sh = __hip_atomic_load(&S[r2 * 4 + h], __ATOMIC_RELAXED, __HIP_MEMORY_SCOPE_AGENT);
                float ch = __hip_atomic_load(&Cnt[r2 * 4 + h], __ATOMIC_RELAXED, __HIP_MEMORY_SCOPE_AGENT);
                numr -= ch * (INVT + logf(sh));
                c += ch;
            }
            if (c > 0.f) { ls -= numr / c; lc += 1.f; }
        }
#pragma unroll
        for (int off2 = 32; off2 > 0; off2 >>= 1) {
            ls += __shfl_xor(ls, off2, 64);
            lc += __shfl_xor(lc, off2, 64);
        }
        if (lane == 0) { rwave[wave] = ls; rwave[4 + wave] = lc; }
        __syncthreads();
        if (tid == 0)
            out[0] = (rwave[0] + rwave[1] + rwave[2] + rwave[3]) /
                     (rwave[4] + rwave[5] + rwave[6] + rwave[7]);
    }
}

extern "C" void kernel_launch(void* const* d_in, const int* in_sizes, int n_in,
                              void* d_out, int out_size, void* d_ws, size_t ws_size,
                              hipStream_t stream) {
    const float* feat = (const float*)d_in[0];    // (2048, 2, 256) f32
    const float* labels = (const float*)d_in[1];  // (2048, 10) f32
    float* out = (float*)d_out;

    char* ws = (char*)d_ws;
    unsigned short* fnb = (unsigned short*)ws;                     // N*E bf16 (2 MB)
    float* S = (float*)(ws + (size_t)NROW * EDIM * sizeof(unsigned short));
    float* Num = S + NROW * 4;
    float* Cnt = Num + NROW;
    float* red = Cnt + NROW * 4;              // (kept for layout; unused)
    unsigned* done = (unsigned*)(red + 2);    // completion counter
    unsigned* bits = done + 1;                // BS label bitmasks

    prep_kernel<<<NROW + 8, 256, 0, stream>>>(feat, labels, fnb, bits, S);
    main_kernel<<<dim3(64, 16), 256, 0, stream>>>(fnb, bits, S, Num, Cnt, done, out);
}

// Round 4
// 164.580 us; speedup vs baseline: 1.2551x; 1.2551x over previous
//
#include <hip/hip_runtime.h>
#include <math.h>

// Problem constants
#define BS    2048            // batch
#define NROW  4096            // B*V = N
#define EDIM  256
#define INVT  (1.0f/0.07f)
#define NBLK  (64*32)         // main grid blocks

typedef float  float4v __attribute__((ext_vector_type(4)));
typedef short  short8v __attribute__((ext_vector_type(8)));

static __device__ __forceinline__ unsigned short f2bf(float x) {
    // round-to-nearest-even f32 -> bf16 (inputs are finite)
    unsigned u = __builtin_bit_cast(unsigned, x);
    u += 0x7fffu + ((u >> 16) & 1u);
    return (unsigned short)(u >> 16);
}

static __device__ __forceinline__ void gload_lds16(const void* g, void* l) {
    __builtin_amdgcn_global_load_lds(
        (const __attribute__((address_space(1))) unsigned int*)g,
        (__attribute__((address_space(3))) unsigned int*)l, 16, 0, 0);
}

// ---------------- prep kernel: normalize + label bits + zero accumulators ----
// blocks 0..4095: row normalize (wave w = head w); blocks 4096..4103: labels + zeroing
__global__ void prep_kernel(const float* __restrict__ feat, const float* __restrict__ labels,
                            unsigned short* __restrict__ fnb, unsigned* __restrict__ bits,
                            float* __restrict__ zacc) {
    const int b = blockIdx.x, t = threadIdx.x;
    if (b < NROW) {
        int bb = b & (BS - 1);
        int v = b >> 11;
        float x = feat[(size_t)bb * (2 * EDIM) + (size_t)v * EDIM + t];
        float ss = x * x;
#pragma unroll
        for (int off = 32; off > 0; off >>= 1)
            ss += __shfl_xor(ss, off, 64);
        float nrm = fmaxf(sqrtf(ss), 1e-12f);
        fnb[(size_t)b * EDIM + t] = f2bf(x / nrm);
    } else {
        int g = (b - NROW) * 256 + t;   // 0..2047
        unsigned bb = 0;
#pragma unroll
        for (int d = 0; d < 10; ++d)
            bb |= (labels[g * 10 + d] != 0.0f ? 1u : 0u) << d;
        bits[g] = bb;
        // zero S (N*4), Num (N), Cnt (N*4), red[2], done[1] = N*9+3 words
        for (int k = g; k < NROW * 9 + 3; k += 2048) zacc[k] = 0.0f;
    }
}

// ---------------- main kernel (round-0 structure + tail fix + fused final) --
// grid (64 i-tiles, 32 j-chunks), block 256 = 4 waves.
// Round-0 tile loop restored verbatim (57us proven): serial stage->barrier->
// compute per 64-row j-tile, 32KiB LDS, dacc[4][4], bounds (256,3), VGPR 84.
// Rounds 1-3 post-mortem: per-block __threadfence() (agent fence = buffer_inv)
// invalidated the XCD L2 ~128x/XCD, evicting L2-resident fnb under all
// co-resident blocks -> 2-3x regression across three otherwise-different
// kernels. This version has NO threadfence: __syncthreads drains each
// thread's vmcnt (atomics acked at coherence point), then a RELEASE-scope
// fetch_add on done (wbl2 writeback only, no invalidate); winner does the
// single acquire.
// Tail fix: round-0's grid 1024 @ 3 blocks/CU = 768 + 256-block tail at
// 1 block/CU (Occ 22% ~= (12+4)/2 waves). 2048 half-size blocks -> 2.67
// rounds, tail cost halved.
// C/D layout (m89/m91): col = lane&15, row = (lane>>4)*4 + reg.
__global__ __launch_bounds__(256, 3) void main_kernel(
    const unsigned short* __restrict__ fnb, const unsigned* __restrict__ bits,
    float* __restrict__ S, float* __restrict__ Num, float* __restrict__ Cnt,
    unsigned* __restrict__ done, float* __restrict__ out) {

    __shared__ unsigned short shB[64 * 256];   // 32 KiB, swizzled granules
    __shared__ float rwave[8];
    __shared__ unsigned lastFlag;

    const int tid  = threadIdx.x;
    const int lane = tid & 63;
    const int wave = tid >> 6;
    const int quad = lane >> 4;
    const int ml   = lane & 15;
    const int xr   = ml & 7;                   // swizzle XOR for this lane's rows
    const int i0   = blockIdx.x * 64 + wave * 16;
    const int jc0  = blockIdx.y * 128;

    // A fragments: af[h][kk], 8 x short8 = 32 VGPRs (rows i0..i0+15)
    short8v af[4][2];
    {
        const unsigned short* ap = fnb + (size_t)(i0 + ml) * EDIM + quad * 8;
#pragma unroll
        for (int h = 0; h < 4; ++h)
#pragma unroll
            for (int kk = 0; kk < 2; ++kk)
                af[h][kk] = *(const short8v*)(ap + h * 64 + kk * 32);
    }

    unsigned ibr[4];
#pragma unroll
    for (int r = 0; r < 4; ++r)
        ibr[r] = bits[(i0 + quad * 4 + r) & (BS - 1)];

    float    Sp[4][4] = {};
    float    np[4] = {};
    unsigned cpk[4] = {};   // per row: 4 x 8-bit argmax-head counts

    for (int t = 0; t < 2; ++t) {
        const int j0 = jc0 + t * 64;
        __syncthreads();   // prior tile's reads done before overwrite
#pragma unroll
        for (int q = 0; q < 8; ++q) {
            const int G   = tid + 256 * q;          // LDS 16B-granule index
            const int row = G >> 5;
            const int gg  = (G & 31) ^ (row & 7);   // global granule (swizzle)
            gload_lds16(fnb + (size_t)(j0 + row) * EDIM + gg * 8, shB + G * 8);
        }
        __syncthreads();   // drains vmcnt -> staged data visible

        unsigned jbr[4];
#pragma unroll
        for (int js = 0; js < 4; ++js)
            jbr[js] = bits[(j0 + js * 16 + ml) & (BS - 1)];

        float4v dacc[4][4];   // [js][h]
#pragma unroll
        for (int js = 0; js < 4; ++js)
#pragma unroll
            for (int h = 0; h < 4; ++h)
                dacc[js][h] = (float4v){0.f, 0.f, 0.f, 0.f};

#pragma unroll
        for (int h = 0; h < 4; ++h)
#pragma unroll
            for (int kk = 0; kk < 2; ++kk) {
                const int gsw = ((h * 8 + kk * 4 + quad) ^ xr) * 8;  // elem offset
#pragma unroll
                for (int js = 0; js < 4; ++js) {
                    short8v bf = *(const short8v*)(shB + (js * 16 + ml) * 256 + gsw);
                    dacc[js][h] = __builtin_amdgcn_mfma_f32_16x16x32_bf16(af[h][kk], bf, dacc[js][h], 0, 0, 0);
                }
            }

        // epilogue: 16 (i,j) pairs per lane, 4 heads each
#pragma unroll
        for (int r = 0; r < 4; ++r) {
            const int i = i0 + quad * 4 + r;
            const unsigned ibit = ibr[r];
#pragma unroll
            for (int js = 0; js < 4; ++js) {
                const int j = j0 + js * 16 + ml;
                const float d0 = dacc[js][0][r];
                const float d1 = dacc[js][1][r];
                const float d2 = dacc[js][2][r];
                const float d3 = dacc[js][3][r];
                // argmax, first index wins ties
                float bd = d0; int bh = 0;
                if (d1 > bd) { bd = d1; bh = 1; }
                if (d2 > bd) { bd = d2; bh = 2; }
                if (d3 > bd) { bd = d3; bh = 3; }
                const bool off = (i != j);
                const float e0 = __expf(fmaf(d0, INVT, -INVT));
                const float e1 = __expf(fmaf(d1, INVT, -INVT));
                const float e2 = __expf(fmaf(d2, INVT, -INVT));
                const float e3 = __expf(fmaf(d3, INVT, -INVT));
                if (off) {
                    Sp[r][0] += e0; Sp[r][1] += e1; Sp[r][2] += e2; Sp[r][3] += e3;
                }
                if (off && (ibit & jbr[js])) {
                    np[r] += bd;              // raw dot; * INVT at flush
                    cpk[r] += 1u << (bh * 8);
                }
            }
        }
    }

    // reduce the 16 lanes sharing each row, then one global atomic per value
#pragma unroll
    for (int r = 0; r < 4; ++r) {
        const int i = i0 + quad * 4 + r;
        float v[9];
        v[0] = np[r];
#pragma unroll
        for (int h = 0; h < 4; ++h) v[1 + h] = Sp[r][h];
#pragma unroll
        for (int h = 0; h < 4; ++h) v[5 + h] = (float)((cpk[r] >> (8 * h)) & 255u);
#pragma unroll
        for (int k = 0; k < 9; ++k) {
            float x = v[k];
            x += __shfl_xor(x, 1, 64);
            x += __shfl_xor(x, 2, 64);
            x += __shfl_xor(x, 4, 64);
            x += __shfl_xor(x, 8, 64);
            v[k] = x;
        }
        if (ml == 0) {
            atomicAdd(&Num[i], v[0] * INVT);
#pragma unroll
            for (int h = 0; h < 4; ++h) atomicAdd(&S[i * 4 + h], v[1 + h]);
#pragma unroll
            for (int h = 0; h < 4; ++h) atomicAdd(&Cnt[i * 4 + h], v[5 + h]);
        }
    }

    // ---------------- fused final reduction (fence-free) ---------------------
    // __syncthreads drains each thread's vmcnt before the barrier (compiler
    // emits s_waitcnt vmcnt(0)), so all this block's atomics are acked at the
    // coherence point. RELEASE fetch_add orders them before the done tick
    // without any cache INVALIDATE (the rounds-1-3 poison).
    __syncthreads();
    if (tid == 0) {
        unsigned old = __hip_atomic_fetch_add(done, 1u, __ATOMIC_RELEASE,
                                              __HIP_MEMORY_SCOPE_AGENT);
        lastFlag = (old == NBLK - 1u) ? 1u : 0u;
    }
    __syncthreads();
    if (lastFlag) {
        if (tid == 0)   // single acquire for the winner block's CU/XCD caches
            (void)__hip_atomic_load(done, __ATOMIC_ACQUIRE, __HIP_MEMORY_SCOPE_AGENT);
        __syncthreads();
        float ls = 0.f, lc = 0.f;
        for (int r2 = tid; r2 < NROW; r2 += 256) {
            // agent-scope atomic loads: bypass non-coherent L1/L2 (values were
            // produced by device-scope atomics from other CUs/XCDs)
            float numr = __hip_atomic_load(&Num[r2], __ATOMIC_RELAXED, __HIP_MEMORY_SCOPE_AGENT);
            float c = 0.f;
#pragma unroll
            for (int h = 0; h < 4; ++h) {
                float sh = __hip_atomic_load(&S[r2 * 4 + h], __ATOMIC_RELAXED, __HIP_MEMORY_SCOPE_AGENT);
                float ch = __hip_atomic_load(&Cnt[r2 * 4 + h], __ATOMIC_RELAXED, __HIP_MEMORY_SCOPE_AGENT);
                numr -= ch * (INVT + logf(sh));
                c += ch;
            }
            if (c > 0.f) { ls -= numr / c; lc += 1.f; }
        }
#pragma unroll
        for (int off2 = 32; off2 > 0; off2 >>= 1) {
            ls += __shfl_xor(ls, off2, 64);
            lc += __shfl_xor(lc, off2, 64);
        }
        if (lane == 0) { rwave[wave] = ls; rwave[4 + wave] = lc; }
        __syncthreads();
        if (tid == 0)
            out[0] = (rwave[0] + rwave[1] + rwave[2] + rwave[3]) /
                     (rwave[4] + rwave[5] + rwave[6] + rwave[7]);
    }
}

extern "C" void kernel_launch(void* const* d_in, const int* in_sizes, int n_in,
                              void* d_out, int out_size, void* d_ws, size_t ws_size,
                              hipStream_t stream) {
    const float* feat = (const float*)d_in[0];    // (2048, 2, 256) f32
    const float* labels = (const float*)d_in[1];  // (2048, 10) f32
    float* out = (float*)d_out;

    char* ws = (char*)d_ws;
    unsigned short* fnb = (unsigned short*)ws;                     // N*E bf16 (2 MB)
    float* S = (float*)(ws + (size_t)NROW * EDIM * sizeof(unsigned short));
    float* Num = S + NROW * 4;
    float* Cnt = Num + NROW;
    float* red = Cnt + NROW * 4;              // (kept for layout/zeroing; unused)
    unsigned* done = (unsigned*)(red + 2);    // completion counter
    unsigned* bits = done + 1;                // BS label bitmasks

    prep_kernel<<<NROW + 8, 256, 0, stream>>>(feat, labels, fnb, bits, S);
    main_kernel<<<dim3(64, 32), 256, 0, stream>>>(fnb, bits, S, Num, Cnt, done, out);
}

// Round 5
// 137.344 us; speedup vs baseline: 1.5040x; 1.1983x over previous
//
#include <hip/hip_runtime.h>
#include <math.h>

// Problem constants
#define BS    2048            // batch
#define NROW  4096            // B*V = N
#define EDIM  256
#define INVT  (1.0f/0.07f)

typedef float  float4v __attribute__((ext_vector_type(4)));
typedef short  short8v __attribute__((ext_vector_type(8)));

static __device__ __forceinline__ unsigned short f2bf(float x) {
    // round-to-nearest-even f32 -> bf16 (inputs are finite)
    unsigned u = __builtin_bit_cast(unsigned, x);
    u += 0x7fffu + ((u >> 16) & 1u);
    return (unsigned short)(u >> 16);
}

static __device__ __forceinline__ void gload_lds16(const void* g, void* l) {
    __builtin_amdgcn_global_load_lds(
        (const __attribute__((address_space(1))) unsigned int*)g,
        (__attribute__((address_space(3))) unsigned int*)l, 16, 0, 0);
}

// ---------------- prep kernel: normalize + label bits + zero accumulators ----
// blocks 0..4095: row normalize; blocks 4096..4103: labels + zeroing
__global__ void prep_kernel(const float* __restrict__ feat, const float* __restrict__ labels,
                            unsigned short* __restrict__ fnb, unsigned* __restrict__ bits,
                            float* __restrict__ zacc) {
    const int b = blockIdx.x, t = threadIdx.x;
    if (b < NROW) {
        int bb = b & (BS - 1);
        int v = b >> 11;
        float x = feat[(size_t)bb * (2 * EDIM) + (size_t)v * EDIM + t];
        float ss = x * x;
#pragma unroll
        for (int off = 32; off > 0; off >>= 1)
            ss += __shfl_xor(ss, off, 64);
        float nrm = fmaxf(sqrtf(ss), 1e-12f);
        fnb[(size_t)b * EDIM + t] = f2bf(x / nrm);
    } else {
        int g = (b - NROW) * 256 + t;   // 0..2047
        unsigned bb = 0;
#pragma unroll
        for (int d = 0; d < 10; ++d)
            bb |= (labels[g * 10 + d] != 0.0f ? 1u : 0u) << d;
        bits[g] = bb;
        // zero S (N*4), Num (N), Cnt (N*4), red[2], done[1] = N*9+3 words
        for (int k = g; k < NROW * 9 + 3; k += 2048) zacc[k] = 0.0f;
    }
}

// ---------------- main kernel (round-0 structure, tail-split grid) ----------
// grid (64 i-tiles, 32 j-chunks), block 256 = 4 waves.  Verbatim round-0
// (57us proven) tile loop; ONLY change vs round 0: j-chunk 256 -> 128
// (2 tiles/block, 2048 blocks).  Round-0's 1024-block grid at 3 blocks/CU ran
// as 768-block round + 256-block latency-naked tail (Occ 21.9% ~= 7/32);
// 2048 half-cost blocks -> 2.67 rounds, tail cost halved.
// NO fused final: rounds 1-4 all carried the per-block done-RMW + fused
// reduction and all ran 113-155us vs round-0's 57 -- that class is dropped;
// final_kernel (separate, 16 blocks) restored verbatim.
// C/D layout (m89/m91): col = lane&15, row = (lane>>4)*4 + reg.
// A/B operand layout: lane l -> m/n = l&15, k = (l>>4)*8 + [0..8).
__global__ __launch_bounds__(256, 3) void main_kernel(
    const unsigned short* __restrict__ fnb, const unsigned* __restrict__ bits,
    float* __restrict__ S, float* __restrict__ Num, float* __restrict__ Cnt) {

    __shared__ unsigned short shB[64 * 256];   // 32 KiB, swizzled granules

    const int tid  = threadIdx.x;
    const int lane = tid & 63;
    const int wave = tid >> 6;
    const int quad = lane >> 4;
    const int ml   = lane & 15;
    const int xr   = ml & 7;                   // swizzle XOR for this lane's rows
    const int i0   = blockIdx.x * 64 + wave * 16;
    const int jc0  = blockIdx.y * 128;

    // A fragments: af[h][kk], 8 x short8 = 32 VGPRs (rows i0..i0+15)
    short8v af[4][2];
    {
        const unsigned short* ap = fnb + (size_t)(i0 + ml) * EDIM + quad * 8;
#pragma unroll
        for (int h = 0; h < 4; ++h)
#pragma unroll
            for (int kk = 0; kk < 2; ++kk)
                af[h][kk] = *(const short8v*)(ap + h * 64 + kk * 32);
    }

    unsigned ibr[4];
#pragma unroll
    for (int r = 0; r < 4; ++r)
        ibr[r] = bits[(i0 + quad * 4 + r) & (BS - 1)];

    float    Sp[4][4] = {};
    float    np[4] = {};
    unsigned cpk[4] = {};   // per row: 4 x 8-bit argmax-head counts (max 16)

    for (int t = 0; t < 2; ++t) {
        const int j0 = jc0 + t * 64;
        __syncthreads();   // prior tile's reads done before overwrite
#pragma unroll
        for (int q = 0; q < 8; ++q) {
            const int G   = tid + 256 * q;          // LDS 16B-granule index
            const int row = G >> 5;
            const int gg  = (G & 31) ^ (row & 7);   // global granule (swizzle)
            gload_lds16(fnb + (size_t)(j0 + row) * EDIM + gg * 8, shB + G * 8);
        }
        __syncthreads();   // drains vmcnt -> staged data visible

        unsigned jbr[4];
#pragma unroll
        for (int js = 0; js < 4; ++js)
            jbr[js] = bits[(j0 + js * 16 + ml) & (BS - 1)];

        float4v dacc[4][4];   // [js][h]
#pragma unroll
        for (int js = 0; js < 4; ++js)
#pragma unroll
            for (int h = 0; h < 4; ++h)
                dacc[js][h] = (float4v){0.f, 0.f, 0.f, 0.f};

#pragma unroll
        for (int h = 0; h < 4; ++h)
#pragma unroll
            for (int kk = 0; kk < 2; ++kk) {
                const int gsw = ((h * 8 + kk * 4 + quad) ^ xr) * 8;  // elem offset
#pragma unroll
                for (int js = 0; js < 4; ++js) {
                    short8v bf = *(const short8v*)(shB + (js * 16 + ml) * 256 + gsw);
                    dacc[js][h] = __builtin_amdgcn_mfma_f32_16x16x32_bf16(af[h][kk], bf, dacc[js][h], 0, 0, 0);
                }
            }

        // epilogue: 16 (i,j) pairs per lane, 4 heads each
#pragma unroll
        for (int r = 0; r < 4; ++r) {
            const int i = i0 + quad * 4 + r;
            const unsigned ibit = ibr[r];
#pragma unroll
            for (int js = 0; js < 4; ++js) {
                const int j = j0 + js * 16 + ml;
                const float d0 = dacc[js][0][r];
                const float d1 = dacc[js][1][r];
                const float d2 = dacc[js][2][r];
                const float d3 = dacc[js][3][r];
                // argmax, first index wins ties
                float bd = d0; int bh = 0;
                if (d1 > bd) { bd = d1; bh = 1; }
                if (d2 > bd) { bd = d2; bh = 2; }
                if (d3 > bd) { bd = d3; bh = 3; }
                const bool off = (i != j);
                const float e0 = __expf(fmaf(d0, INVT, -INVT));
                const float e1 = __expf(fmaf(d1, INVT, -INVT));
                const float e2 = __expf(fmaf(d2, INVT, -INVT));
                const float e3 = __expf(fmaf(d3, INVT, -INVT));
                if (off) {
                    Sp[r][0] += e0; Sp[r][1] += e1; Sp[r][2] += e2; Sp[r][3] += e3;
                }
                if (off && (ibit & jbr[js])) {
                    np[r] += bd;              // raw dot; * INVT at flush
                    cpk[r] += 1u << (bh * 8);
                }
            }
        }
    }

    // reduce the 16 lanes sharing each row, then one global atomic per value
#pragma unroll
    for (int r = 0; r < 4; ++r) {
        const int i = i0 + quad * 4 + r;
        float v[9];
        v[0] = np[r];
#pragma unroll
        for (int h = 0; h < 4; ++h) v[1 + h] = Sp[r][h];
#pragma unroll
        for (int h = 0; h < 4; ++h) v[5 + h] = (float)((cpk[r] >> (8 * h)) & 255u);
#pragma unroll
        for (int k = 0; k < 9; ++k) {
            float x = v[k];
            x += __shfl_xor(x, 1, 64);
            x += __shfl_xor(x, 2, 64);
            x += __shfl_xor(x, 4, 64);
            x += __shfl_xor(x, 8, 64);
            v[k] = x;
        }
        if (ml == 0) {
            atomicAdd(&Num[i], v[0] * INVT);
#pragma unroll
            for (int h = 0; h < 4; ++h) atomicAdd(&S[i * 4 + h], v[1 + h]);
#pragma unroll
            for (int h = 0; h < 4; ++h) atomicAdd(&Cnt[i * 4 + h], v[5 + h]);
        }
    }
}

// ---------------- final reduction: 16 blocks, last block writes out --------
__global__ void final_kernel(const float* __restrict__ S, const float* __restrict__ Num,
                             const float* __restrict__ Cnt, float* __restrict__ red,
                             unsigned* __restrict__ done, float* __restrict__ out) {
    const int tid = threadIdx.x;
    const int i = blockIdx.x * 256 + tid;   // grid 16 x 256 = 4096 rows exactly
    float c = 0.f;
    float numr = Num[i];
#pragma unroll
    for (int h = 0; h < 4; ++h) {
        float sh = S[i * 4 + h];
        float ch = Cnt[i * 4 + h];
        numr -= ch * (INVT + logf(sh));
        c += ch;
    }
    float ls = 0.f, lc = 0.f;
    if (c > 0.f) { ls = -(numr / c); lc = 1.f; }

    __shared__ float rs[256], rc[256];
    rs[tid] = ls; rc[tid] = lc;
    __syncthreads();
    for (int s = 128; s > 0; s >>= 1) {
        if (tid < s) { rs[tid] += rs[tid + s]; rc[tid] += rc[tid + s]; }
        __syncthreads();
    }
    if (tid == 0) {
        atomicAdd(&red[0], rs[0]);
        atomicAdd(&red[1], rc[0]);
        __threadfence();
        if (atomicAdd(done, 1u) == 15u) {
            float s = atomicAdd(&red[0], 0.0f);
            float cc = atomicAdd(&red[1], 0.0f);
            out[0] = s / cc;
        }
    }
}

extern "C" void kernel_launch(void* const* d_in, const int* in_sizes, int n_in,
                              void* d_out, int out_size, void* d_ws, size_t ws_size,
                              hipStream_t stream) {
    const float* feat = (const float*)d_in[0];    // (2048, 2, 256) f32
    const float* labels = (const float*)d_in[1];  // (2048, 10) f32
    float* out = (float*)d_out;

    char* ws = (char*)d_ws;
    unsigned short* fnb = (unsigned short*)ws;                     // N*E bf16 (2 MB)
    float* S = (float*)(ws + (size_t)NROW * EDIM * sizeof(unsigned short));
    float* Num = S + NROW * 4;
    float* Cnt = Num + NROW;
    float* red = Cnt + NROW * 4;              // red[0]=sum, red[1]=count
    unsigned* done = (unsigned*)(red + 2);    // completion counter
    unsigned* bits = done + 1;                // BS label bitmasks

    prep_kernel<<<NROW + 8, 256, 0, stream>>>(feat, labels, fnb, bits, S);
    main_kernel<<<dim3(64, 32), 256, 0, stream>>>(fnb, bits, S, Num, Cnt);
    final_kernel<<<16, 256, 0, stream>>>(S, Num, Cnt, red, done, out);
}

// Round 6
// 109.366 us; speedup vs baseline: 1.8888x; 1.2558x over previous
//
#include <hip/hip_runtime.h>
#include <math.h>

// Problem constants
#define BS    2048            // batch
#define NROW  4096            // B*V = N
#define EDIM  256
#define INVT  (1.0f/0.07f)

typedef float  float4v __attribute__((ext_vector_type(4)));
typedef short  short8v __attribute__((ext_vector_type(8)));

static __device__ __forceinline__ unsigned short f2bf(float x) {
    // round-to-nearest-even f32 -> bf16 (inputs are finite)
    unsigned u = __builtin_bit_cast(unsigned, x);
    u += 0x7fffu + ((u >> 16) & 1u);
    return (unsigned short)(u >> 16);
}

static __device__ __forceinline__ void gload_lds16(const void* g, void* l) {
    __builtin_amdgcn_global_load_lds(
        (const __attribute__((address_space(1))) unsigned int*)g,
        (__attribute__((address_space(3))) unsigned int*)l, 16, 0, 0);
}

// ---------------- prep kernel: normalize + label bits + zero accumulators ----
__global__ void prep_kernel(const float* __restrict__ feat, const float* __restrict__ labels,
                            unsigned short* __restrict__ fnb, unsigned* __restrict__ bits,
                            float* __restrict__ zacc) {
    const int b = blockIdx.x, t = threadIdx.x;
    if (b < NROW) {
        int bb = b & (BS - 1);
        int v = b >> 11;
        float x = feat[(size_t)bb * (2 * EDIM) + (size_t)v * EDIM + t];
        float ss = x * x;
#pragma unroll
        for (int off = 32; off > 0; off >>= 1)
            ss += __shfl_xor(ss, off, 64);
        float nrm = fmaxf(sqrtf(ss), 1e-12f);
        fnb[(size_t)b * EDIM + t] = f2bf(x / nrm);
    } else {
        int g = (b - NROW) * 256 + t;   // 0..2047
        unsigned bb = 0;
#pragma unroll
        for (int d = 0; d < 10; ++d)
            bb |= (labels[g * 10 + d] != 0.0f ? 1u : 0u) << d;
        bits[g] = bb;
        // zero S (N*4), Num (N), Cnt (N*4), red[2], done[1] = N*9+3 words
        for (int k = g; k < NROW * 9 + 3; k += 2048) zacc[k] = 0.0f;
    }
}

// ---------------- main kernel: dbuf subtiles + 4 waves/SIMD ------------------
// grid (64 i-tiles, 16 j-chunks) = 1024 blocks (best-known; r5 proved finer
// grids regress: per-block overhead dominates).  Block 256 = 4 waves.
// j-chunk 256 processed as 8 subtiles of 32 rows, double-buffered 2x16KB:
// STAGE(st+1 -> other buf) issued BEFORE compute(st); ONE barrier per subtile
// whose implicit vmcnt(0) lands after the ds_read+MFMA+epilogue phase (T3
// minimal recipe).  First clean test of this: r1 spilled, r2/r3 carried the
// per-block threadfence (buffer_inv L2-invalidate) poison.
// Register shape co-designed for occupancy: epilogue interleaved per js-half
// so live accumulator is dacc[4] (16 regs); af 32 + Sp 16 + misc ~30 =>
// ~95-105 unified regs => fits the (256,4) cap WITHOUT spilling (r1's spill
// came from the co-compiled fused-final tail, now gone) => 4 waves/SIMD,
// 4 blocks/CU x 256 CU = 1024 = grid: all blocks co-resident, ZERO tail.
// Spill tripwire: if VGPR reads 64 and WRITE_SIZE > 25 MB, revert to (256,3).
// C/D layout (m89/m91): col = lane&15, row = (lane>>4)*4 + reg.
// A/B operand layout: lane l -> m/n = l&15, k = (l>>4)*8 + [0..8).
__global__ __launch_bounds__(256, 4) void main_kernel(
    const unsigned short* __restrict__ fnb, const unsigned* __restrict__ bits,
    float* __restrict__ S, float* __restrict__ Num, float* __restrict__ Cnt) {

    __shared__ unsigned short shB[2][32 * 256];   // 2 x 16 KiB, swizzled granules

    const int tid  = threadIdx.x;
    const int lane = tid & 63;
    const int wave = tid >> 6;
    const int quad = lane >> 4;
    const int ml   = lane & 15;
    const int xr   = ml & 7;                   // swizzle XOR for this lane's rows
    const int i0   = blockIdx.x * 64 + wave * 16;
    const int jc0  = blockIdx.y * 256;

    // A fragments: af[h][kk], 8 x short8 = 32 VGPRs (rows i0..i0+15)
    short8v af[4][2];
    {
        const unsigned short* ap = fnb + (size_t)(i0 + ml) * EDIM + quad * 8;
#pragma unroll
        for (int h = 0; h < 4; ++h)
#pragma unroll
            for (int kk = 0; kk < 2; ++kk)
                af[h][kk] = *(const short8v*)(ap + h * 64 + kk * 32);
    }

    unsigned ibr[4];
#pragma unroll
    for (int r = 0; r < 4; ++r)
        ibr[r] = bits[(i0 + quad * 4 + r) & (BS - 1)];

    float    Sp[4][4] = {};
    float    np[4] = {};
    unsigned cpk[4] = {};   // per row: 4 x 8-bit argmax-head counts (max 16/j-chunk col)

    // stage 32 j-rows (16 KiB) of subtile st into shB[buf]
    auto STAGE = [&](int st, int buf) {
#pragma unroll
        for (int q = 0; q < 4; ++q) {
            const int G   = tid + 256 * q;          // LDS 16B-granule index 0..1023
            const int row = G >> 5;                 // 0..31
            const int gg  = (G & 31) ^ (row & 7);   // global granule (pre-swizzled src)
            gload_lds16(fnb + (size_t)(jc0 + st * 32 + row) * EDIM + gg * 8,
                        &shB[buf][G * 8]);
        }
    };

    STAGE(0, 0);
    __syncthreads();                    // drains vmcnt(0): subtile 0 staged

    for (int st = 0; st < 8; ++st) {
        const int cur = st & 1;
        if (st < 7) STAGE(st + 1, cur ^ 1);   // in flight during compute below
        const int j0 = jc0 + st * 32;

#pragma unroll
        for (int js = 0; js < 2; ++js) {
            const unsigned jb = bits[(j0 + js * 16 + ml) & (BS - 1)];

            float4v dacc[4];   // [h] -- live range = this js-half only (16 regs)
#pragma unroll
            for (int h = 0; h < 4; ++h) dacc[h] = (float4v){0.f, 0.f, 0.f, 0.f};
#pragma unroll
            for (int h = 0; h < 4; ++h)
#pragma unroll
                for (int kk = 0; kk < 2; ++kk) {
                    const int gsw = ((h * 8 + kk * 4 + quad) ^ xr) * 8;  // elem offset
                    short8v bf = *(const short8v*)(&shB[cur][(js * 16 + ml) * 256 + gsw]);
                    dacc[h] = __builtin_amdgcn_mfma_f32_16x16x32_bf16(af[h][kk], bf, dacc[h], 0, 0, 0);
                }

            const int j = j0 + js * 16 + ml;
#pragma unroll
            for (int r = 0; r < 4; ++r) {
                const int i = i0 + quad * 4 + r;
                const float d0 = dacc[0][r];
                const float d1 = dacc[1][r];
                const float d2 = dacc[2][r];
                const float d3 = dacc[3][r];
                // argmax, first index wins ties
                float bd = d0; int bh = 0;
                if (d1 > bd) { bd = d1; bh = 1; }
                if (d2 > bd) { bd = d2; bh = 2; }
                if (d3 > bd) { bd = d3; bh = 3; }
                const bool off = (i != j);
                const float e0 = __expf(fmaf(d0, INVT, -INVT));
                const float e1 = __expf(fmaf(d1, INVT, -INVT));
                const float e2 = __expf(fmaf(d2, INVT, -INVT));
                const float e3 = __expf(fmaf(d3, INVT, -INVT));
                if (off) {
                    Sp[r][0] += e0; Sp[r][1] += e1; Sp[r][2] += e2; Sp[r][3] += e3;
                }
                if (off && (ibr[r] & jb)) {
                    np[r] += bd;              // raw dot; * INVT at flush
                    cpk[r] += 1u << (bh * 8);
                }
            }
        }
        __syncthreads();   // all waves done reading shB[cur]; own STAGE(st+1) drained
    }

    // reduce the 16 lanes sharing each row, then one global atomic per value
#pragma unroll
    for (int r = 0; r < 4; ++r) {
        const int i = i0 + quad * 4 + r;
        float v[9];
        v[0] = np[r];
#pragma unroll
        for (int h = 0; h < 4; ++h) v[1 + h] = Sp[r][h];
#pragma unroll
        for (int h = 0; h < 4; ++h) v[5 + h] = (float)((cpk[r] >> (8 * h)) & 255u);
#pragma unroll
        for (int k = 0; k < 9; ++k) {
            float x = v[k];
            x += __shfl_xor(x, 1, 64);
            x += __shfl_xor(x, 2, 64);
            x += __shfl_xor(x, 4, 64);
            x += __shfl_xor(x, 8, 64);
            v[k] = x;
        }
        if (ml == 0) {
            atomicAdd(&Num[i], v[0] * INVT);
#pragma unroll
            for (int h = 0; h < 4; ++h) atomicAdd(&S[i * 4 + h], v[1 + h]);
#pragma unroll
            for (int h = 0; h < 4; ++h) atomicAdd(&Cnt[i * 4 + h], v[5 + h]);
        }
    }
}

// ---------------- final reduction: 16 blocks, last block writes out --------
__global__ void final_kernel(const float* __restrict__ S, const float* __restrict__ Num,
                             const float* __restrict__ Cnt, float* __restrict__ red,
                             unsigned* __restrict__ done, float* __restrict__ out) {
    const int tid = threadIdx.x;
    const int i = blockIdx.x * 256 + tid;   // grid 16 x 256 = 4096 rows exactly
    float c = 0.f;
    float numr = Num[i];
#pragma unroll
    for (int h = 0; h < 4; ++h) {
        float sh = S[i * 4 + h];
        float ch = Cnt[i * 4 + h];
        numr -= ch * (INVT + logf(sh));
        c += ch;
    }
    float ls = 0.f, lc = 0.f;
    if (c > 0.f) { ls = -(numr / c); lc = 1.f; }

    __shared__ float rs[256], rc[256];
    rs[tid] = ls; rc[tid] = lc;
    __syncthreads();
    for (int s = 128; s > 0; s >>= 1) {
        if (tid < s) { rs[tid] += rs[tid + s]; rc[tid] += rc[tid + s]; }
        __syncthreads();
    }
    if (tid == 0) {
        atomicAdd(&red[0], rs[0]);
        atomicAdd(&red[1], rc[0]);
        __threadfence();
        if (atomicAdd(done, 1u) == 15u) {
            float s = atomicAdd(&red[0], 0.0f);
            float cc = atomicAdd(&red[1], 0.0f);
            out[0] = s / cc;
        }
    }
}

extern "C" void kernel_launch(void* const* d_in, const int* in_sizes, int n_in,
                              void* d_out, int out_size, void* d_ws, size_t ws_size,
                              hipStream_t stream) {
    const float* feat = (const float*)d_in[0];    // (2048, 2, 256) f32
    const float* labels = (const float*)d_in[1];  // (2048, 10) f32
    float* out = (float*)d_out;

    char* ws = (char*)d_ws;
    unsigned short* fnb = (unsigned short*)ws;                     // N*E bf16 (2 MB)
    float* S = (float*)(ws + (size_t)NROW * EDIM * sizeof(unsigned short));
    float* Num = S + NROW * 4;
    float* Cnt = Num + NROW;
    float* red = Cnt + NROW * 4;              // red[0]=sum, red[1]=count
    unsigned* done = (unsigned*)(red + 2);    // completion counter
    unsigned* bits = done + 1;                // BS label bitmasks

    prep_kernel<<<NROW + 8, 256, 0, stream>>>(feat, labels, fnb, bits, S);
    main_kernel<<<dim3(64, 16), 256, 0, stream>>>(fnb, bits, S, Num, Cnt);
    final_kernel<<<16, 256, 0, stream>>>(S, Num, Cnt, red, done, out);
}